// Round 1
// baseline (808.801 us; speedup 1.0000x reference)
//
#include <hip/hip_runtime.h>

#define N_NODES 50000
#define N_EDGES 800000
#define D 64
#define N_LAYERS 3
#define N_GRAPHS 512

// deg[dst] += 1 for each edge
__global__ void deg_kernel(const int* __restrict__ dst, float* __restrict__ deg, int nE) {
    int e = blockIdx.x * blockDim.x + threadIdx.x;
    if (e < nE) atomicAdd(&deg[dst[e]], 1.0f);
}

// deg -> rsqrt(deg + 1)  (self-loop adds 1)
__global__ void dinv_kernel(float* __restrict__ deg, int nN) {
    int i = blockIdx.x * blockDim.x + threadIdx.x;
    if (i < nN) deg[i] = rsqrtf(deg[i] + 1.0f);
}

// hW = h @ W ; agg = hW * dinv^2 + b   (fused GEMM + self-loop init)
// one wave (64 lanes) per row; W staged in LDS; row vals broadcast via shfl
__global__ __launch_bounds__(256) void gemm_selfloop_kernel(
    const float* __restrict__ h, const float* __restrict__ W,
    const float* __restrict__ b, const float* __restrict__ dinv,
    float* __restrict__ hW, float* __restrict__ agg, int nN) {
    __shared__ float Wl[D * D];
    int tid = threadIdx.x;
    #pragma unroll
    for (int i = 0; i < (D * D) / 256; ++i)
        Wl[tid + i * 256] = W[tid + i * 256];
    __syncthreads();
    int wave = tid >> 6;
    int lane = tid & 63;
    int row = blockIdx.x * 4 + wave;
    if (row >= nN) return;
    float hreg = h[row * D + lane];  // lane l holds h[row][l]
    float acc = 0.f;
    #pragma unroll
    for (int k = 0; k < D; ++k) {
        acc += __shfl(hreg, k) * Wl[k * D + lane];
    }
    hW[row * D + lane] = acc;
    float di = dinv[row];
    agg[row * D + lane] = acc * di * di + b[lane];
}

// agg[dst] += hW[src] * dinv[src]*dinv[dst]  — one thread per (edge, dim)
__global__ __launch_bounds__(256) void scatter_kernel(
    const int* __restrict__ src, const int* __restrict__ dst,
    const float* __restrict__ dinv, const float* __restrict__ hW,
    float* __restrict__ agg, int nE) {
    long long tid = (long long)blockIdx.x * 256 + threadIdx.x;
    int e = (int)(tid >> 6);
    int d = (int)(tid & 63);
    if (e >= nE) return;
    int s = src[e], t = dst[e];
    float coeff = dinv[s] * dinv[t];
    atomicAdd(&agg[t * D + d], hW[s * D + d] * coeff);
}

// out[batch[n]] += h[n]; counts[batch[n]] += 1
__global__ __launch_bounds__(256) void pool_kernel(
    const float* __restrict__ h, const int* __restrict__ batch,
    float* __restrict__ out, float* __restrict__ counts, int nN) {
    long long tid = (long long)blockIdx.x * 256 + threadIdx.x;
    int n = (int)(tid >> 6);
    int d = (int)(tid & 63);
    if (n >= nN) return;
    int g = batch[n];
    atomicAdd(&out[g * D + d], h[n * D + d]);
    if (d == 0) atomicAdd(&counts[g], 1.0f);
}

__global__ void div_kernel(float* __restrict__ out, const float* __restrict__ counts) {
    int idx = blockIdx.x * blockDim.x + threadIdx.x;
    if (idx >= N_GRAPHS * D) return;
    int g = idx >> 6;
    out[idx] /= fmaxf(counts[g], 1.0f);
}

extern "C" void kernel_launch(void* const* d_in, const int* in_sizes, int n_in,
                              void* d_out, int out_size, void* d_ws, size_t ws_size,
                              hipStream_t stream) {
    const float* x     = (const float*)d_in[0];
    const float* Ws    = (const float*)d_in[1];
    const float* bs    = (const float*)d_in[2];
    const int*   edge  = (const int*)d_in[3];
    const int*   batch = (const int*)d_in[4];
    const int* src = edge;               // edge_index[0]
    const int* dst = edge + N_EDGES;     // edge_index[1]
    float* out = (float*)d_out;

    float* dinv   = (float*)d_ws;                 // N_NODES
    float* counts = dinv + N_NODES;               // N_GRAPHS
    float* bufA   = counts + N_GRAPHS;            // N_NODES*D (agg / next h)
    float* bufB   = bufA + (size_t)N_NODES * D;   // N_NODES*D (hW)

    hipMemsetAsync(dinv, 0, N_NODES * sizeof(float), stream);
    hipMemsetAsync(counts, 0, N_GRAPHS * sizeof(float), stream);
    hipMemsetAsync(d_out, 0, (size_t)out_size * sizeof(float), stream);

    deg_kernel<<<(N_EDGES + 255) / 256, 256, 0, stream>>>(dst, dinv, N_EDGES);
    dinv_kernel<<<(N_NODES + 255) / 256, 256, 0, stream>>>(dinv, N_NODES);

    const float* h = x;
    float* hW  = bufB;
    float* agg = bufA;
    for (int l = 0; l < N_LAYERS; ++l) {
        gemm_selfloop_kernel<<<(N_NODES + 3) / 4, 256, 0, stream>>>(
            h, Ws + (size_t)l * D * D, bs + (size_t)l * D, dinv, hW, agg, N_NODES);
        long long sthreads = (long long)N_EDGES * 64;
        scatter_kernel<<<(int)((sthreads + 255) / 256), 256, 0, stream>>>(
            src, dst, dinv, hW, agg, N_EDGES);
        h = agg;  // agg(bufA) becomes next layer's input; hW(bufB) is dead
    }

    long long pthreads = (long long)N_NODES * 64;
    pool_kernel<<<(int)((pthreads + 255) / 256), 256, 0, stream>>>(
        h, batch, out, counts, N_NODES);
    div_kernel<<<(N_GRAPHS * D + 255) / 256, 256, 0, stream>>>(out, counts);
}

// Round 2
// 520.417 us; speedup vs baseline: 1.5541x; 1.5541x over previous
//
#include <hip/hip_runtime.h>

#define N_NODES 50000
#define N_EDGES 800000
#define D 64
#define N_LAYERS 3
#define N_GRAPHS 512

// ---- CSR build ----------------------------------------------------------

__global__ void deg_kernel(const int* __restrict__ dst, int* __restrict__ degi, int nE) {
    int e = blockIdx.x * blockDim.x + threadIdx.x;
    if (e < nE) atomicAdd(&degi[dst[e]], 1);
}

// single-block exclusive scan of degi -> offsets[0..nN], cursor copy
__global__ __launch_bounds__(1024) void scan_kernel(
    const int* __restrict__ degi, int* __restrict__ offsets,
    int* __restrict__ cursor, int nN) {
    __shared__ int partial[1024];
    int tid = threadIdx.x;
    const int CHUNK = (nN + 1023) / 1024;
    int beg = tid * CHUNK;
    int end = min(beg + CHUNK, nN);
    int sum = 0;
    for (int i = beg; i < end; ++i) sum += degi[i];
    partial[tid] = sum;
    __syncthreads();
    // Hillis-Steele inclusive scan over 1024 partials
    for (int off = 1; off < 1024; off <<= 1) {
        int v = (tid >= off) ? partial[tid - off] : 0;
        __syncthreads();
        partial[tid] += v;
        __syncthreads();
    }
    int run = (tid == 0) ? 0 : partial[tid - 1];
    for (int i = beg; i < end; ++i) {
        offsets[i] = run;
        cursor[i] = run;
        run += degi[i];
    }
    if (tid == 0) offsets[nN] = partial[1023];
}

__global__ void fill_kernel(const int* __restrict__ src, const int* __restrict__ dst,
                            int* __restrict__ cursor, int* __restrict__ csr_src, int nE) {
    int e = blockIdx.x * blockDim.x + threadIdx.x;
    if (e < nE) {
        int pos = atomicAdd(&cursor[dst[e]], 1);
        csr_src[pos] = src[e];
    }
}

__global__ void dinv_kernel(const int* __restrict__ degi, float* __restrict__ dinv, int nN) {
    int i = blockIdx.x * blockDim.x + threadIdx.x;
    if (i < nN) dinv[i] = rsqrtf((float)degi[i] + 1.0f);
}

// ---- per-layer kernels --------------------------------------------------

// hWs = (h @ W) * dinv[row]   (dinv[src] pre-folded for the gather)
__global__ __launch_bounds__(256) void gemm_kernel(
    const float* __restrict__ h, const float* __restrict__ W,
    const float* __restrict__ dinv, float* __restrict__ hWs, int nN) {
    __shared__ float Wl[D * D];
    int tid = threadIdx.x;
    #pragma unroll
    for (int i = 0; i < (D * D) / 256; ++i)
        Wl[tid + i * 256] = W[tid + i * 256];
    __syncthreads();
    int wave = tid >> 6;
    int lane = tid & 63;
    int row = blockIdx.x * 4 + wave;
    if (row >= nN) return;
    float hreg = h[row * D + lane];
    float acc = 0.f;
    #pragma unroll
    for (int k = 0; k < D; ++k)
        acc += __shfl(hreg, k) * Wl[k * D + lane];
    hWs[row * D + lane] = acc * dinv[row];
}

// h_out[t] = dinv[t] * (hWs[t] + sum_{s in N(t)} hWs[s]) + b
// one wave per dst node, lane = dim; no atomics
__global__ __launch_bounds__(256) void agg_kernel(
    const int* __restrict__ offsets, const int* __restrict__ csr_src,
    const float* __restrict__ hWs, const float* __restrict__ dinv,
    const float* __restrict__ b, float* __restrict__ hout, int nN) {
    int wave = threadIdx.x >> 6;
    int lane = threadIdx.x & 63;
    int t = blockIdx.x * 4 + wave;
    if (t >= nN) return;
    int beg = offsets[t];
    int end = offsets[t + 1];
    float acc = hWs[(size_t)t * D + lane];
    int e = beg;
    for (; e + 3 < end; e += 4) {
        int s0 = csr_src[e], s1 = csr_src[e + 1], s2 = csr_src[e + 2], s3 = csr_src[e + 3];
        float v0 = hWs[(size_t)s0 * D + lane];
        float v1 = hWs[(size_t)s1 * D + lane];
        float v2 = hWs[(size_t)s2 * D + lane];
        float v3 = hWs[(size_t)s3 * D + lane];
        acc += v0 + v1 + v2 + v3;
    }
    for (; e < end; ++e)
        acc += hWs[(size_t)csr_src[e] * D + lane];
    hout[(size_t)t * D + lane] = acc * dinv[t] + b[lane];
}

// ---- pooling (batch is sorted -> binary-search ranges, no atomics) -------

__global__ __launch_bounds__(256) void pool_kernel(
    const float* __restrict__ h, const int* __restrict__ batch,
    float* __restrict__ out, int nN) {
    int wave = threadIdx.x >> 6;
    int lane = threadIdx.x & 63;
    int g = blockIdx.x * 4 + wave;
    if (g >= N_GRAPHS) return;
    // lower_bound(batch, g) / lower_bound(batch, g+1)
    int lo = 0, hi = nN;
    while (lo < hi) { int mid = (lo + hi) >> 1; if (batch[mid] < g) lo = mid + 1; else hi = mid; }
    int beg = lo;
    hi = nN;
    while (lo < hi) { int mid = (lo + hi) >> 1; if (batch[mid] < g + 1) lo = mid + 1; else hi = mid; }
    int end = lo;
    float acc = 0.f;
    for (int n = beg; n < end; ++n)
        acc += h[(size_t)n * D + lane];
    float cnt = (float)(end - beg);
    out[g * D + lane] = acc / fmaxf(cnt, 1.0f);
}

// ---- launch --------------------------------------------------------------

extern "C" void kernel_launch(void* const* d_in, const int* in_sizes, int n_in,
                              void* d_out, int out_size, void* d_ws, size_t ws_size,
                              hipStream_t stream) {
    const float* x     = (const float*)d_in[0];
    const float* Ws    = (const float*)d_in[1];
    const float* bs    = (const float*)d_in[2];
    const int*   edge  = (const int*)d_in[3];
    const int*   batch = (const int*)d_in[4];
    const int* src = edge;            // edge_index[0]
    const int* dst = edge + N_EDGES;  // edge_index[1]
    float* out = (float*)d_out;

    char* p = (char*)d_ws;
    int*   degi    = (int*)p;              p += sizeof(int) * N_NODES;
    int*   offsets = (int*)p;              p += sizeof(int) * (N_NODES + 1);
    int*   cursor  = (int*)p;              p += sizeof(int) * N_NODES;
    int*   csr_src = (int*)p;              p += sizeof(int) * N_EDGES;
    float* dinv    = (float*)p;            p += sizeof(float) * N_NODES;
    float* B1      = (float*)p;            p += sizeof(float) * (size_t)N_NODES * D;
    float* B2      = (float*)p;            p += sizeof(float) * (size_t)N_NODES * D;

    hipMemsetAsync(degi, 0, N_NODES * sizeof(int), stream);

    deg_kernel<<<(N_EDGES + 255) / 256, 256, 0, stream>>>(dst, degi, N_EDGES);
    scan_kernel<<<1, 1024, 0, stream>>>(degi, offsets, cursor, N_NODES);
    dinv_kernel<<<(N_NODES + 255) / 256, 256, 0, stream>>>(degi, dinv, N_NODES);
    fill_kernel<<<(N_EDGES + 255) / 256, 256, 0, stream>>>(src, dst, cursor, csr_src, N_EDGES);

    const float* h = x;
    for (int l = 0; l < N_LAYERS; ++l) {
        gemm_kernel<<<(N_NODES + 3) / 4, 256, 0, stream>>>(
            h, Ws + (size_t)l * D * D, dinv, B1, N_NODES);
        agg_kernel<<<(N_NODES + 3) / 4, 256, 0, stream>>>(
            offsets, csr_src, B1, dinv, bs + (size_t)l * D, B2, N_NODES);
        h = B2;
    }

    pool_kernel<<<(N_GRAPHS + 3) / 4, 256, 0, stream>>>(h, batch, out, N_NODES);
}

// Round 3
// 425.141 us; speedup vs baseline: 1.9024x; 1.2241x over previous
//
#include <hip/hip_runtime.h>

#define N_NODES 50000
#define N_EDGES 800000
#define D 64
#define N_LAYERS 3
#define N_GRAPHS 512

#define SCAN_BLOCK 256
#define N_SCAN_BLOCKS ((N_NODES + SCAN_BLOCK - 1) / SCAN_BLOCK)  // 196

// ---- CSR build ----------------------------------------------------------

__global__ void deg_kernel(const int* __restrict__ dst, int* __restrict__ degi, int nE) {
    int e = blockIdx.x * blockDim.x + threadIdx.x;
    if (e < nE) atomicAdd(&degi[dst[e]], 1);
}

// phase 1: per-block sums of degi
__global__ __launch_bounds__(SCAN_BLOCK) void scan_reduce_kernel(
    const int* __restrict__ degi, int* __restrict__ partials, int nN) {
    __shared__ int sm[SCAN_BLOCK];
    int tid = threadIdx.x;
    int i = blockIdx.x * SCAN_BLOCK + tid;
    sm[tid] = (i < nN) ? degi[i] : 0;
    __syncthreads();
    for (int off = SCAN_BLOCK / 2; off > 0; off >>= 1) {
        if (tid < off) sm[tid] += sm[tid + off];
        __syncthreads();
    }
    if (tid == 0) partials[blockIdx.x] = sm[0];
}

// phase 2: single small block exclusive-scans the partials in place
__global__ __launch_bounds__(SCAN_BLOCK) void scan_partials_kernel(
    int* __restrict__ partials, int nB) {
    __shared__ int sm[SCAN_BLOCK];
    int tid = threadIdx.x;
    sm[tid] = (tid < nB) ? partials[tid] : 0;
    __syncthreads();
    // Hillis-Steele inclusive
    for (int off = 1; off < SCAN_BLOCK; off <<= 1) {
        int v = (tid >= off) ? sm[tid - off] : 0;
        __syncthreads();
        sm[tid] += v;
        __syncthreads();
    }
    if (tid < nB) partials[tid] = (tid == 0) ? 0 : sm[tid - 1];  // exclusive
}

// phase 3: block-level exclusive scan + block base -> offsets, cursor
__global__ __launch_bounds__(SCAN_BLOCK) void scan_final_kernel(
    const int* __restrict__ degi, const int* __restrict__ partials,
    int* __restrict__ offsets, int* __restrict__ cursor, int nN) {
    __shared__ int sm[SCAN_BLOCK];
    int tid = threadIdx.x;
    int i = blockIdx.x * SCAN_BLOCK + tid;
    int myval = (i < nN) ? degi[i] : 0;
    sm[tid] = myval;
    __syncthreads();
    for (int off = 1; off < SCAN_BLOCK; off <<= 1) {
        int v = (tid >= off) ? sm[tid - off] : 0;
        __syncthreads();
        sm[tid] += v;
        __syncthreads();
    }
    int excl = sm[tid] - myval + partials[blockIdx.x];
    if (i < nN) {
        offsets[i] = excl;
        cursor[i] = excl;
        if (i == nN - 1) offsets[nN] = excl + myval;
    }
}

__global__ void fill_kernel(const int* __restrict__ src, const int* __restrict__ dst,
                            int* __restrict__ cursor, int* __restrict__ csr_src, int nE) {
    int e = blockIdx.x * blockDim.x + threadIdx.x;
    if (e < nE) {
        int pos = atomicAdd(&cursor[dst[e]], 1);
        csr_src[pos] = src[e];
    }
}

__global__ void dinv_kernel(const int* __restrict__ degi, float* __restrict__ dinv, int nN) {
    int i = blockIdx.x * blockDim.x + threadIdx.x;
    if (i < nN) dinv[i] = rsqrtf((float)degi[i] + 1.0f);
}

// ---- per-layer kernels --------------------------------------------------

// hWs = (h @ W) * dinv[row]   (dinv[src] pre-folded for the gather)
__global__ __launch_bounds__(256) void gemm_kernel(
    const float* __restrict__ h, const float* __restrict__ W,
    const float* __restrict__ dinv, float* __restrict__ hWs, int nN) {
    __shared__ float Wl[D * D];
    int tid = threadIdx.x;
    #pragma unroll
    for (int i = 0; i < (D * D) / 256; ++i)
        Wl[tid + i * 256] = W[tid + i * 256];
    __syncthreads();
    int wave = tid >> 6;
    int lane = tid & 63;
    int row = blockIdx.x * 4 + wave;
    if (row >= nN) return;
    float hreg = h[row * D + lane];
    float acc = 0.f;
    #pragma unroll
    for (int k = 0; k < D; ++k)
        acc += __shfl(hreg, k) * Wl[k * D + lane];
    hWs[row * D + lane] = acc * dinv[row];
}

// h_out[t] = dinv[t] * (hWs[t] + sum_{s in N(t)} hWs[s]) + b
// one wave per dst node, lane = dim; no atomics
__global__ __launch_bounds__(256) void agg_kernel(
    const int* __restrict__ offsets, const int* __restrict__ csr_src,
    const float* __restrict__ hWs, const float* __restrict__ dinv,
    const float* __restrict__ b, float* __restrict__ hout, int nN) {
    int wave = threadIdx.x >> 6;
    int lane = threadIdx.x & 63;
    int t = blockIdx.x * 4 + wave;
    if (t >= nN) return;
    int beg = offsets[t];
    int end = offsets[t + 1];
    float acc = hWs[(size_t)t * D + lane];
    int e = beg;
    for (; e + 3 < end; e += 4) {
        int s0 = csr_src[e], s1 = csr_src[e + 1], s2 = csr_src[e + 2], s3 = csr_src[e + 3];
        float v0 = hWs[(size_t)s0 * D + lane];
        float v1 = hWs[(size_t)s1 * D + lane];
        float v2 = hWs[(size_t)s2 * D + lane];
        float v3 = hWs[(size_t)s3 * D + lane];
        acc += v0 + v1 + v2 + v3;
    }
    for (; e < end; ++e)
        acc += hWs[(size_t)csr_src[e] * D + lane];
    hout[(size_t)t * D + lane] = acc * dinv[t] + b[lane];
}

// ---- pooling (batch is sorted -> binary-search ranges, no atomics) -------

__global__ __launch_bounds__(256) void pool_kernel(
    const float* __restrict__ h, const int* __restrict__ batch,
    float* __restrict__ out, int nN) {
    int wave = threadIdx.x >> 6;
    int lane = threadIdx.x & 63;
    int g = blockIdx.x * 4 + wave;
    if (g >= N_GRAPHS) return;
    int lo = 0, hi = nN;
    while (lo < hi) { int mid = (lo + hi) >> 1; if (batch[mid] < g) lo = mid + 1; else hi = mid; }
    int beg = lo;
    hi = nN;
    while (lo < hi) { int mid = (lo + hi) >> 1; if (batch[mid] < g + 1) lo = mid + 1; else hi = mid; }
    int end = lo;
    float acc = 0.f;
    for (int n = beg; n < end; ++n)
        acc += h[(size_t)n * D + lane];
    float cnt = (float)(end - beg);
    out[g * D + lane] = acc / fmaxf(cnt, 1.0f);
}

// ---- launch --------------------------------------------------------------

extern "C" void kernel_launch(void* const* d_in, const int* in_sizes, int n_in,
                              void* d_out, int out_size, void* d_ws, size_t ws_size,
                              hipStream_t stream) {
    const float* x     = (const float*)d_in[0];
    const float* Ws    = (const float*)d_in[1];
    const float* bs    = (const float*)d_in[2];
    const int*   edge  = (const int*)d_in[3];
    const int*   batch = (const int*)d_in[4];
    const int* src = edge;            // edge_index[0]
    const int* dst = edge + N_EDGES;  // edge_index[1]
    float* out = (float*)d_out;

    char* p = (char*)d_ws;
    int*   degi     = (int*)p;             p += sizeof(int) * N_NODES;
    int*   offsets  = (int*)p;             p += sizeof(int) * (N_NODES + 1);
    int*   cursor   = (int*)p;             p += sizeof(int) * N_NODES;
    int*   partials = (int*)p;             p += sizeof(int) * N_SCAN_BLOCKS;
    int*   csr_src  = (int*)p;             p += sizeof(int) * N_EDGES;
    float* dinv     = (float*)p;           p += sizeof(float) * N_NODES;
    float* B1       = (float*)p;           p += sizeof(float) * (size_t)N_NODES * D;
    float* B2       = (float*)p;           p += sizeof(float) * (size_t)N_NODES * D;

    hipMemsetAsync(degi, 0, N_NODES * sizeof(int), stream);

    deg_kernel<<<(N_EDGES + 255) / 256, 256, 0, stream>>>(dst, degi, N_EDGES);
    scan_reduce_kernel<<<N_SCAN_BLOCKS, SCAN_BLOCK, 0, stream>>>(degi, partials, N_NODES);
    scan_partials_kernel<<<1, SCAN_BLOCK, 0, stream>>>(partials, N_SCAN_BLOCKS);
    scan_final_kernel<<<N_SCAN_BLOCKS, SCAN_BLOCK, 0, stream>>>(degi, partials, offsets, cursor, N_NODES);
    dinv_kernel<<<(N_NODES + 255) / 256, 256, 0, stream>>>(degi, dinv, N_NODES);
    fill_kernel<<<(N_EDGES + 255) / 256, 256, 0, stream>>>(src, dst, cursor, csr_src, N_EDGES);

    const float* h = x;
    for (int l = 0; l < N_LAYERS; ++l) {
        gemm_kernel<<<(N_NODES + 3) / 4, 256, 0, stream>>>(
            h, Ws + (size_t)l * D * D, dinv, B1, N_NODES);
        agg_kernel<<<(N_NODES + 3) / 4, 256, 0, stream>>>(
            offsets, csr_src, B1, dinv, bs + (size_t)l * D, B2, N_NODES);
        h = B2;
    }

    pool_kernel<<<(N_GRAPHS + 3) / 4, 256, 0, stream>>>(h, batch, out, N_NODES);
}

// Round 4
// 355.049 us; speedup vs baseline: 2.2780x; 1.1974x over previous
//
#include <hip/hip_runtime.h>

#define N_NODES 50000
#define N_EDGES 800000
#define D 64
#define N_LAYERS 3
#define N_GRAPHS 512

#define SCAN_BLOCK 256
#define N_SCAN_BLOCKS ((N_NODES + SCAN_BLOCK - 1) / SCAN_BLOCK)  // 196

// ---- CSR build ----------------------------------------------------------

__global__ void deg_kernel(const int* __restrict__ dst, int* __restrict__ degi, int nE) {
    int e = blockIdx.x * blockDim.x + threadIdx.x;
    if (e < nE) atomicAdd(&degi[dst[e]], 1);
}

__global__ __launch_bounds__(SCAN_BLOCK) void scan_reduce_kernel(
    const int* __restrict__ degi, int* __restrict__ partials, int nN) {
    __shared__ int sm[SCAN_BLOCK];
    int tid = threadIdx.x;
    int i = blockIdx.x * SCAN_BLOCK + tid;
    sm[tid] = (i < nN) ? degi[i] : 0;
    __syncthreads();
    for (int off = SCAN_BLOCK / 2; off > 0; off >>= 1) {
        if (tid < off) sm[tid] += sm[tid + off];
        __syncthreads();
    }
    if (tid == 0) partials[blockIdx.x] = sm[0];
}

__global__ __launch_bounds__(SCAN_BLOCK) void scan_partials_kernel(
    int* __restrict__ partials, int nB) {
    __shared__ int sm[SCAN_BLOCK];
    int tid = threadIdx.x;
    sm[tid] = (tid < nB) ? partials[tid] : 0;
    __syncthreads();
    for (int off = 1; off < SCAN_BLOCK; off <<= 1) {
        int v = (tid >= off) ? sm[tid - off] : 0;
        __syncthreads();
        sm[tid] += v;
        __syncthreads();
    }
    if (tid < nB) partials[tid] = (tid == 0) ? 0 : sm[tid - 1];  // exclusive
}

__global__ __launch_bounds__(SCAN_BLOCK) void scan_final_kernel(
    const int* __restrict__ degi, const int* __restrict__ partials,
    int* __restrict__ offsets, int* __restrict__ cursor, int nN) {
    __shared__ int sm[SCAN_BLOCK];
    int tid = threadIdx.x;
    int i = blockIdx.x * SCAN_BLOCK + tid;
    int myval = (i < nN) ? degi[i] : 0;
    sm[tid] = myval;
    __syncthreads();
    for (int off = 1; off < SCAN_BLOCK; off <<= 1) {
        int v = (tid >= off) ? sm[tid - off] : 0;
        __syncthreads();
        sm[tid] += v;
        __syncthreads();
    }
    int excl = sm[tid] - myval + partials[blockIdx.x];
    if (i < nN) {
        offsets[i] = excl;
        cursor[i] = excl;
        if (i == nN - 1) offsets[nN] = excl + myval;
    }
}

__global__ void fill_kernel(const int* __restrict__ src, const int* __restrict__ dst,
                            int* __restrict__ cursor, int* __restrict__ csr_src, int nE) {
    int e = blockIdx.x * blockDim.x + threadIdx.x;
    if (e < nE) {
        int pos = atomicAdd(&cursor[dst[e]], 1);
        csr_src[pos] = src[e];
    }
}

__global__ void dinv_kernel(const int* __restrict__ degi, float* __restrict__ dinv, int nN) {
    int i = blockIdx.x * blockDim.x + threadIdx.x;
    if (i < nN) dinv[i] = rsqrtf((float)degi[i] + 1.0f);
}

// ---- per-layer kernels --------------------------------------------------

// hWs = (h @ W) * dinv[row]  — register-blocked tiled fp32 GEMM
// block = 256 threads, tile = 64 rows x 64 cols, 4x4 register tile/thread
#define GROWS 64
#define LPAD 68  // row stride in floats: 272B, 16B-aligned, 2-way bank alias (free)
__global__ __launch_bounds__(256) void gemm_kernel(
    const float* __restrict__ h, const float* __restrict__ W,
    const float* __restrict__ dinv, float* __restrict__ hWs, int nN) {
    __shared__ float hs[GROWS][LPAD];
    __shared__ float Wl[D][LPAD];
    int tid = threadIdx.x;
    int row0 = blockIdx.x * GROWS;
    #pragma unroll
    for (int i = 0; i < 4; ++i) {
        int idx4 = tid + i * 256;        // 0..1023 float4 slots
        int r = idx4 >> 4;
        int c4 = (idx4 & 15) << 2;
        *(float4*)&Wl[r][c4] = *(const float4*)&W[r * D + c4];
        float4 hv = make_float4(0.f, 0.f, 0.f, 0.f);
        int gr = row0 + r;
        if (gr < nN) hv = *(const float4*)&h[(size_t)gr * D + c4];
        *(float4*)&hs[r][c4] = hv;
    }
    __syncthreads();
    int r0 = (tid >> 4) << 2;
    int c0 = (tid & 15) << 2;
    float acc[4][4];
    #pragma unroll
    for (int i = 0; i < 4; ++i)
        #pragma unroll
        for (int j = 0; j < 4; ++j) acc[i][j] = 0.f;
    #pragma unroll
    for (int kk = 0; kk < D; kk += 4) {
        float4 a0 = *(float4*)&hs[r0 + 0][kk];
        float4 a1 = *(float4*)&hs[r0 + 1][kk];
        float4 a2 = *(float4*)&hs[r0 + 2][kk];
        float4 a3 = *(float4*)&hs[r0 + 3][kk];
        float4 w0 = *(float4*)&Wl[kk + 0][c0];
        float4 w1 = *(float4*)&Wl[kk + 1][c0];
        float4 w2 = *(float4*)&Wl[kk + 2][c0];
        float4 w3 = *(float4*)&Wl[kk + 3][c0];
        float* w0p = &w0.x; float* w1p = &w1.x; float* w2p = &w2.x; float* w3p = &w3.x;
        float4 av[4] = {a0, a1, a2, a3};
        #pragma unroll
        for (int i = 0; i < 4; ++i) {
            #pragma unroll
            for (int j = 0; j < 4; ++j) {
                acc[i][j] += av[i].x * w0p[j] + av[i].y * w1p[j]
                           + av[i].z * w2p[j] + av[i].w * w3p[j];
            }
        }
    }
    #pragma unroll
    for (int i = 0; i < 4; ++i) {
        int gr = row0 + r0 + i;
        if (gr < nN) {
            float s = dinv[gr];
            float4 o = make_float4(acc[i][0] * s, acc[i][1] * s,
                                   acc[i][2] * s, acc[i][3] * s);
            *(float4*)&hWs[(size_t)gr * D + c0] = o;
        }
    }
}

// h_out[t] = dinv[t] * (hWs[t] + sum_{s in N(t)} hWs[s]) + b
__global__ __launch_bounds__(256) void agg_kernel(
    const int* __restrict__ offsets, const int* __restrict__ csr_src,
    const float* __restrict__ hWs, const float* __restrict__ dinv,
    const float* __restrict__ b, float* __restrict__ hout, int nN) {
    int wave = threadIdx.x >> 6;
    int lane = threadIdx.x & 63;
    int t = blockIdx.x * 4 + wave;
    if (t >= nN) return;
    int beg = offsets[t];
    int end = offsets[t + 1];
    float acc = hWs[(size_t)t * D + lane];
    int e = beg;
    for (; e + 3 < end; e += 4) {
        int s0 = csr_src[e], s1 = csr_src[e + 1], s2 = csr_src[e + 2], s3 = csr_src[e + 3];
        float v0 = hWs[(size_t)s0 * D + lane];
        float v1 = hWs[(size_t)s1 * D + lane];
        float v2 = hWs[(size_t)s2 * D + lane];
        float v3 = hWs[(size_t)s3 * D + lane];
        acc += v0 + v1 + v2 + v3;
    }
    for (; e < end; ++e)
        acc += hWs[(size_t)csr_src[e] * D + lane];
    hout[(size_t)t * D + lane] = acc * dinv[t] + b[lane];
}

// ---- pooling -------------------------------------------------------------

__global__ __launch_bounds__(256) void pool_kernel(
    const float* __restrict__ h, const int* __restrict__ batch,
    float* __restrict__ out, int nN) {
    int wave = threadIdx.x >> 6;
    int lane = threadIdx.x & 63;
    int g = blockIdx.x * 4 + wave;
    if (g >= N_GRAPHS) return;
    int lo = 0, hi = nN;
    while (lo < hi) { int mid = (lo + hi) >> 1; if (batch[mid] < g) lo = mid + 1; else hi = mid; }
    int beg = lo;
    hi = nN;
    while (lo < hi) { int mid = (lo + hi) >> 1; if (batch[mid] < g + 1) lo = mid + 1; else hi = mid; }
    int end = lo;
    float acc = 0.f;
    for (int n = beg; n < end; ++n)
        acc += h[(size_t)n * D + lane];
    float cnt = (float)(end - beg);
    out[g * D + lane] = acc / fmaxf(cnt, 1.0f);
}

// ---- launch --------------------------------------------------------------

extern "C" void kernel_launch(void* const* d_in, const int* in_sizes, int n_in,
                              void* d_out, int out_size, void* d_ws, size_t ws_size,
                              hipStream_t stream) {
    const float* x     = (const float*)d_in[0];
    const float* Ws    = (const float*)d_in[1];
    const float* bs    = (const float*)d_in[2];
    const int*   edge  = (const int*)d_in[3];
    const int*   batch = (const int*)d_in[4];
    const int* src = edge;            // edge_index[0]
    const int* dst = edge + N_EDGES;  // edge_index[1]
    float* out = (float*)d_out;

    char* p = (char*)d_ws;
    int*   degi     = (int*)p;             p += sizeof(int) * N_NODES;
    int*   offsets  = (int*)p;             p += sizeof(int) * (N_NODES + 1);
    int*   cursor   = (int*)p;             p += sizeof(int) * N_NODES;
    int*   partials = (int*)p;             p += sizeof(int) * N_SCAN_BLOCKS;
    int*   csr_src  = (int*)p;             p += sizeof(int) * N_EDGES;
    float* dinv     = (float*)p;           p += sizeof(float) * N_NODES;
    float* B1       = (float*)p;           p += sizeof(float) * (size_t)N_NODES * D;
    float* B2       = (float*)p;           p += sizeof(float) * (size_t)N_NODES * D;

    hipMemsetAsync(degi, 0, N_NODES * sizeof(int), stream);

    deg_kernel<<<(N_EDGES + 255) / 256, 256, 0, stream>>>(dst, degi, N_EDGES);
    scan_reduce_kernel<<<N_SCAN_BLOCKS, SCAN_BLOCK, 0, stream>>>(degi, partials, N_NODES);
    scan_partials_kernel<<<1, SCAN_BLOCK, 0, stream>>>(partials, N_SCAN_BLOCKS);
    scan_final_kernel<<<N_SCAN_BLOCKS, SCAN_BLOCK, 0, stream>>>(degi, partials, offsets, cursor, N_NODES);
    dinv_kernel<<<(N_NODES + 255) / 256, 256, 0, stream>>>(degi, dinv, N_NODES);
    fill_kernel<<<(N_EDGES + 255) / 256, 256, 0, stream>>>(src, dst, cursor, csr_src, N_EDGES);

    const float* h = x;
    for (int l = 0; l < N_LAYERS; ++l) {
        gemm_kernel<<<(N_NODES + GROWS - 1) / GROWS, 256, 0, stream>>>(
            h, Ws + (size_t)l * D * D, dinv, B1, N_NODES);
        agg_kernel<<<(N_NODES + 3) / 4, 256, 0, stream>>>(
            offsets, csr_src, B1, dinv, bs + (size_t)l * D, B2, N_NODES);
        h = B2;
    }

    pool_kernel<<<(N_GRAPHS + 3) / 4, 256, 0, stream>>>(h, batch, out, N_NODES);
}

// Round 5
// 299.645 us; speedup vs baseline: 2.6992x; 1.1849x over previous
//
#include <hip/hip_runtime.h>

#define N_NODES 50000
#define N_EDGES 800000
#define D 64
#define N_LAYERS 3
#define N_GRAPHS 512

#define NB 196            // buckets = ceil(50000/256); bucket = dst >> 8
#define BCAP 5120         // per-bucket capacity: mean 4082, sigma 64 -> 16 sigma
#define P3_CHUNK 2048
#define N_P3_WG ((N_EDGES + P3_CHUNK - 1) / P3_CHUNK)  // 391

// ---- CSR build: two-level counting sort ---------------------------------

// pass 1: bucket edges. LDS histogram -> one global atomic per (WG,bucket),
// then place packed (src | dst_low<<16) into bucket segments.
__global__ __launch_bounds__(256) void bucket_scatter_kernel(
    const int* __restrict__ src, const int* __restrict__ dst,
    int* __restrict__ bucket_fill, int* __restrict__ bucketArr, int nE) {
    __shared__ int hist[NB], base[NB], cur[NB];
    int tid = threadIdx.x;
    if (tid < NB) hist[tid] = 0;
    __syncthreads();
    int s8[8], d8[8];
    bool v8[8];
    int ebase = blockIdx.x * P3_CHUNK + tid;
    #pragma unroll
    for (int i = 0; i < 8; ++i) {
        int e = ebase + i * 256;
        v8[i] = (e < nE);
        if (v8[i]) {
            s8[i] = src[e];
            d8[i] = dst[e];
            atomicAdd(&hist[d8[i] >> 8], 1);
        }
    }
    __syncthreads();
    if (tid < NB) {
        base[tid] = atomicAdd(&bucket_fill[tid], hist[tid]);
        cur[tid] = 0;
    }
    __syncthreads();
    #pragma unroll
    for (int i = 0; i < 8; ++i) {
        if (v8[i]) {
            int b = d8[i] >> 8;
            int r = atomicAdd(&cur[b], 1);
            int pos = base[b] + r;
            if (pos < BCAP)  // safety guard; statistically never taken
                bucketArr[b * BCAP + pos] = (s8[i] & 0xFFFF) | ((d8[i] & 0xFF) << 16);
        }
    }
}

// pass 2: exclusive scan of bucket counts -> CSR base per bucket
__global__ __launch_bounds__(256) void bucket_scan_kernel(
    const int* __restrict__ bucket_fill, int* __restrict__ bucket_base,
    int* __restrict__ offsets) {
    __shared__ int sm[256];
    int tid = threadIdx.x;
    int own = (tid < NB) ? bucket_fill[tid] : 0;
    sm[tid] = own;
    __syncthreads();
    for (int off = 1; off < 256; off <<= 1) {
        int v = (tid >= off) ? sm[tid - off] : 0;
        __syncthreads();
        sm[tid] += v;
        __syncthreads();
    }
    if (tid < NB) bucket_base[tid] = sm[tid] - own;  // exclusive
    if (tid == 0) offsets[N_NODES] = N_EDGES;
}

// pass 3: per-bucket local counting sort -> offsets, dinv, csr_src
// each WG owns one contiguous CSR segment -> coalesced, single-owner writes
__global__ __launch_bounds__(256) void bucket_csr_kernel(
    const int* __restrict__ bucket_fill, const int* __restrict__ bucket_base,
    const int* __restrict__ bucketArr,
    int* __restrict__ offsets, int* __restrict__ csr_src,
    float* __restrict__ dinv) {
    __shared__ int ldeg[256], lsc[256], lcur[256];
    int b = blockIdx.x;
    int tid = threadIdx.x;
    int cnt = min(bucket_fill[b], BCAP);
    int cbase = bucket_base[b];
    const int* seg = bucketArr + b * BCAP;
    ldeg[tid] = 0;
    __syncthreads();
    for (int e = tid; e < cnt; e += 256)
        atomicAdd(&ldeg[(seg[e] >> 16) & 0xFF], 1);
    __syncthreads();
    int own = ldeg[tid];
    lsc[tid] = own;
    __syncthreads();
    for (int off = 1; off < 256; off <<= 1) {
        int v = (tid >= off) ? lsc[tid - off] : 0;
        __syncthreads();
        lsc[tid] += v;
        __syncthreads();
    }
    int excl = lsc[tid] - own;
    int node = b * 256 + tid;
    if (node < N_NODES) {
        offsets[node] = cbase + excl;
        dinv[node] = rsqrtf((float)own + 1.0f);
    }
    lcur[tid] = cbase + excl;
    __syncthreads();
    for (int e = tid; e < cnt; e += 256) {
        int p = seg[e];
        int pos = atomicAdd(&lcur[(p >> 16) & 0xFF], 1);
        csr_src[pos] = p & 0xFFFF;
    }
}

// ---- per-layer kernels --------------------------------------------------

// hWs = (h @ W) * dinv[row]  — register-blocked tiled fp32 GEMM
#define GROWS 64
#define LPAD 68
__global__ __launch_bounds__(256) void gemm_kernel(
    const float* __restrict__ h, const float* __restrict__ W,
    const float* __restrict__ dinv, float* __restrict__ hWs, int nN) {
    __shared__ float hs[GROWS][LPAD];
    __shared__ float Wl[D][LPAD];
    int tid = threadIdx.x;
    int row0 = blockIdx.x * GROWS;
    #pragma unroll
    for (int i = 0; i < 4; ++i) {
        int idx4 = tid + i * 256;
        int r = idx4 >> 4;
        int c4 = (idx4 & 15) << 2;
        *(float4*)&Wl[r][c4] = *(const float4*)&W[r * D + c4];
        float4 hv = make_float4(0.f, 0.f, 0.f, 0.f);
        int gr = row0 + r;
        if (gr < nN) hv = *(const float4*)&h[(size_t)gr * D + c4];
        *(float4*)&hs[r][c4] = hv;
    }
    __syncthreads();
    int r0 = (tid >> 4) << 2;
    int c0 = (tid & 15) << 2;
    float acc[4][4];
    #pragma unroll
    for (int i = 0; i < 4; ++i)
        #pragma unroll
        for (int j = 0; j < 4; ++j) acc[i][j] = 0.f;
    #pragma unroll
    for (int kk = 0; kk < D; kk += 4) {
        float4 a0 = *(float4*)&hs[r0 + 0][kk];
        float4 a1 = *(float4*)&hs[r0 + 1][kk];
        float4 a2 = *(float4*)&hs[r0 + 2][kk];
        float4 a3 = *(float4*)&hs[r0 + 3][kk];
        float4 w0 = *(float4*)&Wl[kk + 0][c0];
        float4 w1 = *(float4*)&Wl[kk + 1][c0];
        float4 w2 = *(float4*)&Wl[kk + 2][c0];
        float4 w3 = *(float4*)&Wl[kk + 3][c0];
        float* w0p = &w0.x; float* w1p = &w1.x; float* w2p = &w2.x; float* w3p = &w3.x;
        float4 av[4] = {a0, a1, a2, a3};
        #pragma unroll
        for (int i = 0; i < 4; ++i) {
            #pragma unroll
            for (int j = 0; j < 4; ++j) {
                acc[i][j] += av[i].x * w0p[j] + av[i].y * w1p[j]
                           + av[i].z * w2p[j] + av[i].w * w3p[j];
            }
        }
    }
    #pragma unroll
    for (int i = 0; i < 4; ++i) {
        int gr = row0 + r0 + i;
        if (gr < nN) {
            float s = dinv[gr];
            float4 o = make_float4(acc[i][0] * s, acc[i][1] * s,
                                   acc[i][2] * s, acc[i][3] * s);
            *(float4*)&hWs[(size_t)gr * D + c0] = o;
        }
    }
}

// h_out[t] = dinv[t] * (hWs[t] + sum_{s in N(t)} hWs[s]) + b
__global__ __launch_bounds__(256) void agg_kernel(
    const int* __restrict__ offsets, const int* __restrict__ csr_src,
    const float* __restrict__ hWs, const float* __restrict__ dinv,
    const float* __restrict__ b, float* __restrict__ hout, int nN) {
    int wave = threadIdx.x >> 6;
    int lane = threadIdx.x & 63;
    int t = blockIdx.x * 4 + wave;
    if (t >= nN) return;
    int beg = offsets[t];
    int end = offsets[t + 1];
    float acc = hWs[(size_t)t * D + lane];
    int e = beg;
    for (; e + 3 < end; e += 4) {
        int s0 = csr_src[e], s1 = csr_src[e + 1], s2 = csr_src[e + 2], s3 = csr_src[e + 3];
        float v0 = hWs[(size_t)s0 * D + lane];
        float v1 = hWs[(size_t)s1 * D + lane];
        float v2 = hWs[(size_t)s2 * D + lane];
        float v3 = hWs[(size_t)s3 * D + lane];
        acc += v0 + v1 + v2 + v3;
    }
    for (; e < end; ++e)
        acc += hWs[(size_t)csr_src[e] * D + lane];
    hout[(size_t)t * D + lane] = acc * dinv[t] + b[lane];
}

// ---- pooling -------------------------------------------------------------

__global__ __launch_bounds__(256) void pool_kernel(
    const float* __restrict__ h, const int* __restrict__ batch,
    float* __restrict__ out, int nN) {
    int wave = threadIdx.x >> 6;
    int lane = threadIdx.x & 63;
    int g = blockIdx.x * 4 + wave;
    if (g >= N_GRAPHS) return;
    int lo = 0, hi = nN;
    while (lo < hi) { int mid = (lo + hi) >> 1; if (batch[mid] < g) lo = mid + 1; else hi = mid; }
    int beg = lo;
    hi = nN;
    while (lo < hi) { int mid = (lo + hi) >> 1; if (batch[mid] < g + 1) lo = mid + 1; else hi = mid; }
    int end = lo;
    float acc = 0.f;
    for (int n = beg; n < end; ++n)
        acc += h[(size_t)n * D + lane];
    float cnt = (float)(end - beg);
    out[g * D + lane] = acc / fmaxf(cnt, 1.0f);
}

// ---- launch --------------------------------------------------------------

extern "C" void kernel_launch(void* const* d_in, const int* in_sizes, int n_in,
                              void* d_out, int out_size, void* d_ws, size_t ws_size,
                              hipStream_t stream) {
    const float* x     = (const float*)d_in[0];
    const float* Ws    = (const float*)d_in[1];
    const float* bs    = (const float*)d_in[2];
    const int*   edge  = (const int*)d_in[3];
    const int*   batch = (const int*)d_in[4];
    const int* src = edge;            // edge_index[0]
    const int* dst = edge + N_EDGES;  // edge_index[1]
    float* out = (float*)d_out;

    char* p = (char*)d_ws;
    int*   offsets     = (int*)p;      p += sizeof(int) * (N_NODES + 1);
    int*   csr_src     = (int*)p;      p += sizeof(int) * N_EDGES;
    int*   bucket_fill = (int*)p;      p += sizeof(int) * NB;
    int*   bucket_base = (int*)p;      p += sizeof(int) * NB;
    float* dinv        = (float*)p;    p += sizeof(float) * N_NODES;
    float* B1          = (float*)p;    p += sizeof(float) * (size_t)N_NODES * D;
    float* B2          = (float*)p;    p += sizeof(float) * (size_t)N_NODES * D;
    // bucketArr (NB*BCAP ints = 4.0 MB) overlays B2: dead before first agg write
    int* bucketArr = (int*)B2;

    hipMemsetAsync(bucket_fill, 0, NB * sizeof(int), stream);

    bucket_scatter_kernel<<<N_P3_WG, 256, 0, stream>>>(src, dst, bucket_fill, bucketArr, N_EDGES);
    bucket_scan_kernel<<<1, 256, 0, stream>>>(bucket_fill, bucket_base, offsets);
    bucket_csr_kernel<<<NB, 256, 0, stream>>>(bucket_fill, bucket_base, bucketArr,
                                              offsets, csr_src, dinv);

    const float* h = x;
    for (int l = 0; l < N_LAYERS; ++l) {
        gemm_kernel<<<(N_NODES + GROWS - 1) / GROWS, 256, 0, stream>>>(
            h, Ws + (size_t)l * D * D, dinv, B1, N_NODES);
        agg_kernel<<<(N_NODES + 3) / 4, 256, 0, stream>>>(
            offsets, csr_src, B1, dinv, bs + (size_t)l * D, B2, N_NODES);
        h = B2;
    }

    pool_kernel<<<(N_GRAPHS + 3) / 4, 256, 0, stream>>>(h, batch, out, N_NODES);
}

// Round 6
// 265.223 us; speedup vs baseline: 3.0495x; 1.1298x over previous
//
#include <hip/hip_runtime.h>

#define N_NODES 50000
#define N_EDGES 800000
#define D 64
#define N_LAYERS 3
#define N_GRAPHS 512

#define NB 196            // buckets = ceil(50000/256); bucket = dst >> 8
#define BCAP 5120         // per-bucket capacity: mean 4082, sigma 64 -> 16 sigma
#define P3_CHUNK 2048
#define N_P3_WG ((N_EDGES + P3_CHUNK - 1) / P3_CHUNK)  // 391

// ---- CSR build: two-level counting sort ---------------------------------

__global__ __launch_bounds__(256) void bucket_scatter_kernel(
    const int* __restrict__ src, const int* __restrict__ dst,
    int* __restrict__ bucket_fill, int* __restrict__ bucketArr, int nE) {
    __shared__ int hist[NB], base[NB], cur[NB];
    int tid = threadIdx.x;
    if (tid < NB) hist[tid] = 0;
    __syncthreads();
    int s8[8], d8[8];
    bool v8[8];
    int ebase = blockIdx.x * P3_CHUNK + tid;
    #pragma unroll
    for (int i = 0; i < 8; ++i) {
        int e = ebase + i * 256;
        v8[i] = (e < nE);
        if (v8[i]) {
            s8[i] = src[e];
            d8[i] = dst[e];
            atomicAdd(&hist[d8[i] >> 8], 1);
        }
    }
    __syncthreads();
    if (tid < NB) {
        base[tid] = atomicAdd(&bucket_fill[tid], hist[tid]);
        cur[tid] = 0;
    }
    __syncthreads();
    #pragma unroll
    for (int i = 0; i < 8; ++i) {
        if (v8[i]) {
            int b = d8[i] >> 8;
            int r = atomicAdd(&cur[b], 1);
            int pos = base[b] + r;
            if (pos < BCAP)
                bucketArr[b * BCAP + pos] = (s8[i] & 0xFFFF) | ((d8[i] & 0xFF) << 16);
        }
    }
}

__global__ __launch_bounds__(256) void bucket_scan_kernel(
    const int* __restrict__ bucket_fill, int* __restrict__ bucket_base,
    int* __restrict__ offsets) {
    __shared__ int sm[256];
    int tid = threadIdx.x;
    int own = (tid < NB) ? bucket_fill[tid] : 0;
    sm[tid] = own;
    __syncthreads();
    for (int off = 1; off < 256; off <<= 1) {
        int v = (tid >= off) ? sm[tid - off] : 0;
        __syncthreads();
        sm[tid] += v;
        __syncthreads();
    }
    if (tid < NB) bucket_base[tid] = sm[tid] - own;  // exclusive
    if (tid == 0) offsets[N_NODES] = N_EDGES;
}

__global__ __launch_bounds__(256) void bucket_csr_kernel(
    const int* __restrict__ bucket_fill, const int* __restrict__ bucket_base,
    const int* __restrict__ bucketArr,
    int* __restrict__ offsets, int* __restrict__ csr_src,
    float* __restrict__ dinv) {
    __shared__ int ldeg[256], lsc[256], lcur[256];
    int b = blockIdx.x;
    int tid = threadIdx.x;
    int cnt = min(bucket_fill[b], BCAP);
    int cbase = bucket_base[b];
    const int* seg = bucketArr + b * BCAP;
    ldeg[tid] = 0;
    __syncthreads();
    for (int e = tid; e < cnt; e += 256)
        atomicAdd(&ldeg[(seg[e] >> 16) & 0xFF], 1);
    __syncthreads();
    int own = ldeg[tid];
    lsc[tid] = own;
    __syncthreads();
    for (int off = 1; off < 256; off <<= 1) {
        int v = (tid >= off) ? lsc[tid - off] : 0;
        __syncthreads();
        lsc[tid] += v;
        __syncthreads();
    }
    int excl = lsc[tid] - own;
    int node = b * 256 + tid;
    if (node < N_NODES) {
        offsets[node] = cbase + excl;
        dinv[node] = rsqrtf((float)own + 1.0f);
    }
    lcur[tid] = cbase + excl;
    __syncthreads();
    for (int e = tid; e < cnt; e += 256) {
        int p = seg[e];
        int pos = atomicAdd(&lcur[(p >> 16) & 0xFF], 1);
        csr_src[pos] = p & 0xFFFF;
    }
}

// ---- graph boundaries from sorted batch (node-parallel, no searches) -----

__global__ __launch_bounds__(256) void gbounds_kernel(
    const int* __restrict__ batch, int* __restrict__ gstart, int nN) {
    int i = blockIdx.x * 256 + threadIdx.x;
    if (i >= nN) return;
    int b = batch[i];
    int prev = (i == 0) ? -1 : batch[i - 1];
    for (int g = prev + 1; g <= b; ++g) gstart[g] = i;
    if (i == nN - 1) {
        for (int g = b + 1; g <= N_GRAPHS; ++g) gstart[g] = nN;
    }
}

// ---- per-layer kernels --------------------------------------------------

#define GROWS 64
#define LPAD 68
__global__ __launch_bounds__(256) void gemm_kernel(
    const float* __restrict__ h, const float* __restrict__ W,
    const float* __restrict__ dinv, float* __restrict__ hWs, int nN) {
    __shared__ float hs[GROWS][LPAD];
    __shared__ float Wl[D][LPAD];
    int tid = threadIdx.x;
    int row0 = blockIdx.x * GROWS;
    #pragma unroll
    for (int i = 0; i < 4; ++i) {
        int idx4 = tid + i * 256;
        int r = idx4 >> 4;
        int c4 = (idx4 & 15) << 2;
        *(float4*)&Wl[r][c4] = *(const float4*)&W[r * D + c4];
        float4 hv = make_float4(0.f, 0.f, 0.f, 0.f);
        int gr = row0 + r;
        if (gr < nN) hv = *(const float4*)&h[(size_t)gr * D + c4];
        *(float4*)&hs[r][c4] = hv;
    }
    __syncthreads();
    int r0 = (tid >> 4) << 2;
    int c0 = (tid & 15) << 2;
    float acc[4][4];
    #pragma unroll
    for (int i = 0; i < 4; ++i)
        #pragma unroll
        for (int j = 0; j < 4; ++j) acc[i][j] = 0.f;
    #pragma unroll
    for (int kk = 0; kk < D; kk += 4) {
        float4 a0 = *(float4*)&hs[r0 + 0][kk];
        float4 a1 = *(float4*)&hs[r0 + 1][kk];
        float4 a2 = *(float4*)&hs[r0 + 2][kk];
        float4 a3 = *(float4*)&hs[r0 + 3][kk];
        float4 w0 = *(float4*)&Wl[kk + 0][c0];
        float4 w1 = *(float4*)&Wl[kk + 1][c0];
        float4 w2 = *(float4*)&Wl[kk + 2][c0];
        float4 w3 = *(float4*)&Wl[kk + 3][c0];
        float* w0p = &w0.x; float* w1p = &w1.x; float* w2p = &w2.x; float* w3p = &w3.x;
        float4 av[4] = {a0, a1, a2, a3};
        #pragma unroll
        for (int i = 0; i < 4; ++i) {
            #pragma unroll
            for (int j = 0; j < 4; ++j) {
                acc[i][j] += av[i].x * w0p[j] + av[i].y * w1p[j]
                           + av[i].z * w2p[j] + av[i].w * w3p[j];
            }
        }
    }
    #pragma unroll
    for (int i = 0; i < 4; ++i) {
        int gr = row0 + r0 + i;
        if (gr < nN) {
            float s = dinv[gr];
            float4 o = make_float4(acc[i][0] * s, acc[i][1] * s,
                                   acc[i][2] * s, acc[i][3] * s);
            *(float4*)&hWs[(size_t)gr * D + c0] = o;
        }
    }
}

// h_out[t] = dinv[t] * (hWs[t] + sum_{s in N(t)} hWs[s]) + b
__global__ __launch_bounds__(256) void agg_kernel(
    const int* __restrict__ offsets, const int* __restrict__ csr_src,
    const float* __restrict__ hWs, const float* __restrict__ dinv,
    const float* __restrict__ b, float* __restrict__ hout, int nN) {
    int wave = threadIdx.x >> 6;
    int lane = threadIdx.x & 63;
    int t = blockIdx.x * 4 + wave;
    if (t >= nN) return;
    int beg = offsets[t];
    int end = offsets[t + 1];
    float acc = hWs[(size_t)t * D + lane];
    int e = beg;
    for (; e + 3 < end; e += 4) {
        int s0 = csr_src[e], s1 = csr_src[e + 1], s2 = csr_src[e + 2], s3 = csr_src[e + 3];
        float v0 = hWs[(size_t)s0 * D + lane];
        float v1 = hWs[(size_t)s1 * D + lane];
        float v2 = hWs[(size_t)s2 * D + lane];
        float v3 = hWs[(size_t)s3 * D + lane];
        acc += v0 + v1 + v2 + v3;
    }
    for (; e < end; ++e)
        acc += hWs[(size_t)csr_src[e] * D + lane];
    hout[(size_t)t * D + lane] = acc * dinv[t] + b[lane];
}

// ---- pooling: one block per graph, 4 waves, LDS reduce -------------------

__global__ __launch_bounds__(256) void pool_kernel(
    const float* __restrict__ h, const int* __restrict__ gstart,
    float* __restrict__ out) {
    __shared__ float sm[4][D];
    int g = blockIdx.x;
    int wave = threadIdx.x >> 6;
    int lane = threadIdx.x & 63;
    int beg = gstart[g];
    int end = gstart[g + 1];
    float acc = 0.f;
    int n = beg + wave;
    for (; n + 12 < end; n += 16) {
        float a0 = h[(size_t)(n)      * D + lane];
        float a1 = h[(size_t)(n + 4)  * D + lane];
        float a2 = h[(size_t)(n + 8)  * D + lane];
        float a3 = h[(size_t)(n + 12) * D + lane];
        acc += a0 + a1 + a2 + a3;
    }
    for (; n < end; n += 4)
        acc += h[(size_t)n * D + lane];
    sm[wave][lane] = acc;
    __syncthreads();
    if (wave == 0) {
        float s = sm[0][lane] + sm[1][lane] + sm[2][lane] + sm[3][lane];
        float cnt = (float)(end - beg);
        out[g * D + lane] = s / fmaxf(cnt, 1.0f);
    }
}

// ---- launch --------------------------------------------------------------

extern "C" void kernel_launch(void* const* d_in, const int* in_sizes, int n_in,
                              void* d_out, int out_size, void* d_ws, size_t ws_size,
                              hipStream_t stream) {
    const float* x     = (const float*)d_in[0];
    const float* Ws    = (const float*)d_in[1];
    const float* bs    = (const float*)d_in[2];
    const int*   edge  = (const int*)d_in[3];
    const int*   batch = (const int*)d_in[4];
    const int* src = edge;            // edge_index[0]
    const int* dst = edge + N_EDGES;  // edge_index[1]
    float* out = (float*)d_out;

    char* p = (char*)d_ws;
    int*   offsets     = (int*)p;      p += sizeof(int) * (N_NODES + 1);
    int*   csr_src     = (int*)p;      p += sizeof(int) * N_EDGES;
    int*   bucket_fill = (int*)p;      p += sizeof(int) * NB;
    int*   bucket_base = (int*)p;      p += sizeof(int) * NB;
    int*   gstart      = (int*)p;      p += sizeof(int) * (N_GRAPHS + 1);
    float* dinv        = (float*)p;    p += sizeof(float) * N_NODES;
    float* B1          = (float*)p;    p += sizeof(float) * (size_t)N_NODES * D;
    float* B2          = (float*)p;    p += sizeof(float) * (size_t)N_NODES * D;
    // bucketArr (NB*BCAP ints = 4.0 MB) overlays B2: dead before first agg write
    int* bucketArr = (int*)B2;

    hipMemsetAsync(bucket_fill, 0, NB * sizeof(int), stream);

    bucket_scatter_kernel<<<N_P3_WG, 256, 0, stream>>>(src, dst, bucket_fill, bucketArr, N_EDGES);
    bucket_scan_kernel<<<1, 256, 0, stream>>>(bucket_fill, bucket_base, offsets);
    bucket_csr_kernel<<<NB, 256, 0, stream>>>(bucket_fill, bucket_base, bucketArr,
                                              offsets, csr_src, dinv);
    gbounds_kernel<<<(N_NODES + 255) / 256, 256, 0, stream>>>(batch, gstart, N_NODES);

    const float* h = x;
    for (int l = 0; l < N_LAYERS; ++l) {
        gemm_kernel<<<(N_NODES + GROWS - 1) / GROWS, 256, 0, stream>>>(
            h, Ws + (size_t)l * D * D, dinv, B1, N_NODES);
        agg_kernel<<<(N_NODES + 3) / 4, 256, 0, stream>>>(
            offsets, csr_src, B1, dinv, bs + (size_t)l * D, B2, N_NODES);
        h = B2;
    }

    pool_kernel<<<N_GRAPHS, 256, 0, stream>>>(h, gstart, out);
}

// Round 7
// 227.967 us; speedup vs baseline: 3.5479x; 1.1634x over previous
//
#include <hip/hip_runtime.h>

#define N_NODES 50000
#define N_EDGES 800000
#define D 64
#define N_LAYERS 3
#define N_GRAPHS 512

#define NB 196            // buckets = ceil(50000/256); bucket = dst >> 8
#define BCAP 5120         // per-bucket capacity: mean 4082, sigma 64 -> 16 sigma
#define P3_CHUNK 2048
#define N_P3_WG ((N_EDGES + P3_CHUNK - 1) / P3_CHUNK)  // 391

// ---- CSR build: two-level counting sort ---------------------------------

__global__ __launch_bounds__(256) void bucket_scatter_kernel(
    const int* __restrict__ src, const int* __restrict__ dst,
    int* __restrict__ bucket_fill, int* __restrict__ bucketArr, int nE) {
    __shared__ int hist[NB], base[NB], cur[NB];
    int tid = threadIdx.x;
    if (tid < NB) hist[tid] = 0;
    __syncthreads();
    int s8[8], d8[8];
    bool v8[8];
    int ebase = blockIdx.x * P3_CHUNK + tid;
    #pragma unroll
    for (int i = 0; i < 8; ++i) {
        int e = ebase + i * 256;
        v8[i] = (e < nE);
        if (v8[i]) {
            s8[i] = src[e];
            d8[i] = dst[e];
            atomicAdd(&hist[d8[i] >> 8], 1);
        }
    }
    __syncthreads();
    if (tid < NB) {
        base[tid] = atomicAdd(&bucket_fill[tid], hist[tid]);
        cur[tid] = 0;
    }
    __syncthreads();
    #pragma unroll
    for (int i = 0; i < 8; ++i) {
        if (v8[i]) {
            int b = d8[i] >> 8;
            int r = atomicAdd(&cur[b], 1);
            int pos = base[b] + r;
            if (pos < BCAP)
                bucketArr[b * BCAP + pos] = (s8[i] & 0xFFFF) | ((d8[i] & 0xFF) << 16);
        }
    }
}

__global__ __launch_bounds__(256) void bucket_scan_kernel(
    const int* __restrict__ bucket_fill, int* __restrict__ bucket_base,
    int* __restrict__ offsets) {
    __shared__ int sm[256];
    int tid = threadIdx.x;
    int own = (tid < NB) ? bucket_fill[tid] : 0;
    sm[tid] = own;
    __syncthreads();
    for (int off = 1; off < 256; off <<= 1) {
        int v = (tid >= off) ? sm[tid - off] : 0;
        __syncthreads();
        sm[tid] += v;
        __syncthreads();
    }
    if (tid < NB) bucket_base[tid] = sm[tid] - own;  // exclusive
    if (tid == 0) offsets[N_NODES] = N_EDGES;
}

__global__ __launch_bounds__(256) void bucket_csr_kernel(
    const int* __restrict__ bucket_fill, const int* __restrict__ bucket_base,
    const int* __restrict__ bucketArr,
    int* __restrict__ offsets, int* __restrict__ csr_src,
    float* __restrict__ dinv) {
    __shared__ int ldeg[256], lsc[256], lcur[256];
    int b = blockIdx.x;
    int tid = threadIdx.x;
    int cnt = min(bucket_fill[b], BCAP);
    int cbase = bucket_base[b];
    const int* seg = bucketArr + b * BCAP;
    ldeg[tid] = 0;
    __syncthreads();
    for (int e = tid; e < cnt; e += 256)
        atomicAdd(&ldeg[(seg[e] >> 16) & 0xFF], 1);
    __syncthreads();
    int own = ldeg[tid];
    lsc[tid] = own;
    __syncthreads();
    for (int off = 1; off < 256; off <<= 1) {
        int v = (tid >= off) ? lsc[tid - off] : 0;
        __syncthreads();
        lsc[tid] += v;
        __syncthreads();
    }
    int excl = lsc[tid] - own;
    int node = b * 256 + tid;
    if (node < N_NODES) {
        offsets[node] = cbase + excl;
        dinv[node] = rsqrtf((float)own + 1.0f);
    }
    lcur[tid] = cbase + excl;
    __syncthreads();
    for (int e = tid; e < cnt; e += 256) {
        int p = seg[e];
        int pos = atomicAdd(&lcur[(p >> 16) & 0xFF], 1);
        csr_src[pos] = p & 0xFFFF;
    }
}

// ---- graph boundaries from sorted batch ----------------------------------

__global__ __launch_bounds__(256) void gbounds_kernel(
    const int* __restrict__ batch, int* __restrict__ gstart, int nN) {
    int i = blockIdx.x * 256 + threadIdx.x;
    if (i >= nN) return;
    int b = batch[i];
    int prev = (i == 0) ? -1 : batch[i - 1];
    for (int g = prev + 1; g <= b; ++g) gstart[g] = i;
    if (i == nN - 1) {
        for (int g = b + 1; g <= N_GRAPHS; ++g) gstart[g] = nN;
    }
}

// ---- per-layer kernels --------------------------------------------------

#define GROWS 64
#define LPAD 68
__global__ __launch_bounds__(256) void gemm_kernel(
    const float* __restrict__ h, const float* __restrict__ W,
    const float* __restrict__ dinv, float* __restrict__ hWs, int nN) {
    __shared__ float hs[GROWS][LPAD];
    __shared__ float Wl[D][LPAD];
    int tid = threadIdx.x;
    int row0 = blockIdx.x * GROWS;
    #pragma unroll
    for (int i = 0; i < 4; ++i) {
        int idx4 = tid + i * 256;
        int r = idx4 >> 4;
        int c4 = (idx4 & 15) << 2;
        *(float4*)&Wl[r][c4] = *(const float4*)&W[r * D + c4];
        float4 hv = make_float4(0.f, 0.f, 0.f, 0.f);
        int gr = row0 + r;
        if (gr < nN) hv = *(const float4*)&h[(size_t)gr * D + c4];
        *(float4*)&hs[r][c4] = hv;
    }
    __syncthreads();
    int r0 = (tid >> 4) << 2;
    int c0 = (tid & 15) << 2;
    float acc[4][4];
    #pragma unroll
    for (int i = 0; i < 4; ++i)
        #pragma unroll
        for (int j = 0; j < 4; ++j) acc[i][j] = 0.f;
    #pragma unroll
    for (int kk = 0; kk < D; kk += 4) {
        float4 a0 = *(float4*)&hs[r0 + 0][kk];
        float4 a1 = *(float4*)&hs[r0 + 1][kk];
        float4 a2 = *(float4*)&hs[r0 + 2][kk];
        float4 a3 = *(float4*)&hs[r0 + 3][kk];
        float4 w0 = *(float4*)&Wl[kk + 0][c0];
        float4 w1 = *(float4*)&Wl[kk + 1][c0];
        float4 w2 = *(float4*)&Wl[kk + 2][c0];
        float4 w3 = *(float4*)&Wl[kk + 3][c0];
        float* w0p = &w0.x; float* w1p = &w1.x; float* w2p = &w2.x; float* w3p = &w3.x;
        float4 av[4] = {a0, a1, a2, a3};
        #pragma unroll
        for (int i = 0; i < 4; ++i) {
            #pragma unroll
            for (int j = 0; j < 4; ++j) {
                acc[i][j] += av[i].x * w0p[j] + av[i].y * w1p[j]
                           + av[i].z * w2p[j] + av[i].w * w3p[j];
            }
        }
    }
    #pragma unroll
    for (int i = 0; i < 4; ++i) {
        int gr = row0 + r0 + i;
        if (gr < nN) {
            float s = dinv[gr];
            float4 o = make_float4(acc[i][0] * s, acc[i][1] * s,
                                   acc[i][2] * s, acc[i][3] * s);
            *(float4*)&hWs[(size_t)gr * D + c0] = o;
        }
    }
}

// h_out[t] = dinv[t] * (hWs[t] + sum_{s in N(t)} hWs[s]) + b
// one wave per dst node; 16 lanes per edge (float4 gather), 4 edges/instr
__global__ __launch_bounds__(256) void agg_kernel(
    const int* __restrict__ offsets, const int* __restrict__ csr_src,
    const float* __restrict__ hWs, const float* __restrict__ dinv,
    const float* __restrict__ b, float* __restrict__ hout, int nN) {
    int wave = threadIdx.x >> 6;
    int lane = threadIdx.x & 63;
    int t = blockIdx.x * 4 + wave;
    if (t >= nN) return;
    int beg = offsets[t];
    int end = offsets[t + 1];
    int grp = lane >> 4;   // edge slot 0..3
    int q4  = (lane & 15) << 2;  // dim offset
    float4 acc0 = make_float4(0.f, 0.f, 0.f, 0.f);
    float4 acc1 = make_float4(0.f, 0.f, 0.f, 0.f);
    int e = beg + grp;
    for (; e + 4 < end; e += 8) {
        int s0 = csr_src[e];
        int s1 = csr_src[e + 4];
        float4 v0 = *(const float4*)&hWs[(size_t)s0 * D + q4];
        float4 v1 = *(const float4*)&hWs[(size_t)s1 * D + q4];
        acc0.x += v0.x; acc0.y += v0.y; acc0.z += v0.z; acc0.w += v0.w;
        acc1.x += v1.x; acc1.y += v1.y; acc1.z += v1.z; acc1.w += v1.w;
    }
    if (e < end) {
        int s0 = csr_src[e];
        float4 v0 = *(const float4*)&hWs[(size_t)s0 * D + q4];
        acc0.x += v0.x; acc0.y += v0.y; acc0.z += v0.z; acc0.w += v0.w;
    }
    float4 acc = make_float4(acc0.x + acc1.x, acc0.y + acc1.y,
                             acc0.z + acc1.z, acc0.w + acc1.w);
    // fold the 4 edge-slots: lanes {l, l^16, l^32, l^48} share dim-quad
    #pragma unroll
    for (int m = 16; m < 64; m <<= 1) {
        acc.x += __shfl_xor(acc.x, m);
        acc.y += __shfl_xor(acc.y, m);
        acc.z += __shfl_xor(acc.z, m);
        acc.w += __shfl_xor(acc.w, m);
    }
    if (grp == 0) {
        float4 self = *(const float4*)&hWs[(size_t)t * D + q4];
        float dt = dinv[t];
        float4 bb = *(const float4*)&b[q4];
        float4 o;
        o.x = (acc.x + self.x) * dt + bb.x;
        o.y = (acc.y + self.y) * dt + bb.y;
        o.z = (acc.z + self.z) * dt + bb.z;
        o.w = (acc.w + self.w) * dt + bb.w;
        *(float4*)&hout[(size_t)t * D + q4] = o;
    }
}

// ---- pooling: one block per graph, 4 waves, LDS reduce -------------------

__global__ __launch_bounds__(256) void pool_kernel(
    const float* __restrict__ h, const int* __restrict__ gstart,
    float* __restrict__ out) {
    __shared__ float sm[4][D];
    int g = blockIdx.x;
    int wave = threadIdx.x >> 6;
    int lane = threadIdx.x & 63;
    int beg = gstart[g];
    int end = gstart[g + 1];
    float acc = 0.f;
    int n = beg + wave;
    for (; n + 12 < end; n += 16) {
        float a0 = h[(size_t)(n)      * D + lane];
        float a1 = h[(size_t)(n + 4)  * D + lane];
        float a2 = h[(size_t)(n + 8)  * D + lane];
        float a3 = h[(size_t)(n + 12) * D + lane];
        acc += a0 + a1 + a2 + a3;
    }
    for (; n < end; n += 4)
        acc += h[(size_t)n * D + lane];
    sm[wave][lane] = acc;
    __syncthreads();
    if (wave == 0) {
        float s = sm[0][lane] + sm[1][lane] + sm[2][lane] + sm[3][lane];
        float cnt = (float)(end - beg);
        out[g * D + lane] = s / fmaxf(cnt, 1.0f);
    }
}

// ---- launch --------------------------------------------------------------

#define WS_ALIGN(p) ((char*)(((size_t)(p) + 255) & ~(size_t)255))

extern "C" void kernel_launch(void* const* d_in, const int* in_sizes, int n_in,
                              void* d_out, int out_size, void* d_ws, size_t ws_size,
                              hipStream_t stream) {
    const float* x     = (const float*)d_in[0];
    const float* Ws    = (const float*)d_in[1];
    const float* bs    = (const float*)d_in[2];
    const int*   edge  = (const int*)d_in[3];
    const int*   batch = (const int*)d_in[4];
    const int* src = edge;            // edge_index[0]
    const int* dst = edge + N_EDGES;  // edge_index[1]
    float* out = (float*)d_out;

    char* p = (char*)d_ws;
    int* offsets     = (int*)p;      p = WS_ALIGN(p + sizeof(int) * (N_NODES + 1));
    int* csr_src     = (int*)p;      p = WS_ALIGN(p + sizeof(int) * N_EDGES);
    int* bucket_fill = (int*)p;      p = WS_ALIGN(p + sizeof(int) * NB);
    int* bucket_base = (int*)p;      p = WS_ALIGN(p + sizeof(int) * NB);
    int* gstart      = (int*)p;      p = WS_ALIGN(p + sizeof(int) * (N_GRAPHS + 1));
    float* dinv      = (float*)p;    p = WS_ALIGN(p + sizeof(float) * N_NODES);
    float* B1        = (float*)p;    p = WS_ALIGN(p + sizeof(float) * (size_t)N_NODES * D);
    float* B2        = (float*)p;
    // bucketArr (NB*BCAP ints = 4.0 MB) overlays B2: dead before first agg write
    int* bucketArr = (int*)B2;

    hipMemsetAsync(bucket_fill, 0, NB * sizeof(int), stream);

    bucket_scatter_kernel<<<N_P3_WG, 256, 0, stream>>>(src, dst, bucket_fill, bucketArr, N_EDGES);
    bucket_scan_kernel<<<1, 256, 0, stream>>>(bucket_fill, bucket_base, offsets);
    bucket_csr_kernel<<<NB, 256, 0, stream>>>(bucket_fill, bucket_base, bucketArr,
                                              offsets, csr_src, dinv);
    gbounds_kernel<<<(N_NODES + 255) / 256, 256, 0, stream>>>(batch, gstart, N_NODES);

    const float* h = x;
    for (int l = 0; l < N_LAYERS; ++l) {
        gemm_kernel<<<(N_NODES + GROWS - 1) / GROWS, 256, 0, stream>>>(
            h, Ws + (size_t)l * D * D, dinv, B1, N_NODES);
        agg_kernel<<<(N_NODES + 3) / 4, 256, 0, stream>>>(
            offsets, csr_src, B1, dinv, bs + (size_t)l * D, B2, N_NODES);
        h = B2;
    }

    pool_kernel<<<N_GRAPHS, 256, 0, stream>>>(h, gstart, out);
}